// Round 1
// baseline (142.784 us; speedup 1.0000x reference)
//
#include <hip/hip_runtime.h>
#include <hip/hip_bf16.h>

typedef __attribute__((ext_vector_type(4))) float f32x4;
typedef __attribute__((ext_vector_type(8))) __bf16 bf16x8;

#define AS1 __attribute__((address_space(1)))
#define AS3 __attribute__((address_space(3)))

#define DDIM 512
#define BK 64

// ---------------- Kernel 1: normalize rows + positive-pair dot ----------------
// One block per sample k (N blocks, 256 threads). Writes z[k] and z[N+k] (bf16)
// and pd[k] = cos(emb_i[k], emb_j[k]).
__global__ __launch_bounds__(256) void norm_pd_kernel(
    const float* __restrict__ ei, const float* __restrict__ ej,
    __hip_bfloat16* __restrict__ z, float* __restrict__ pd, int N) {
  const int k = blockIdx.x;
  const int t = threadIdx.x;
  const float2 a = *reinterpret_cast<const float2*>(ei + (size_t)k * DDIM + t * 2);
  const float2 b = *reinterpret_cast<const float2*>(ej + (size_t)k * DDIM + t * 2);
  float sii = a.x * a.x + a.y * a.y;
  float sjj = b.x * b.x + b.y * b.y;
  float sij = a.x * b.x + a.y * b.y;
#pragma unroll
  for (int off = 32; off; off >>= 1) {
    sii += __shfl_down(sii, off);
    sjj += __shfl_down(sjj, off);
    sij += __shfl_down(sij, off);
  }
  __shared__ float red[3][4];
  if ((t & 63) == 0) { red[0][t >> 6] = sii; red[1][t >> 6] = sjj; red[2][t >> 6] = sij; }
  __syncthreads();
  sii = red[0][0] + red[0][1] + red[0][2] + red[0][3];
  sjj = red[1][0] + red[1][1] + red[1][2] + red[1][3];
  sij = red[2][0] + red[2][1] + red[2][2] + red[2][3];
  const float rsi = rsqrtf(sii), rsj = rsqrtf(sjj);
  __hip_bfloat162 zi, zj;
  zi.x = __float2bfloat16(a.x * rsi); zi.y = __float2bfloat16(a.y * rsi);
  zj.x = __float2bfloat16(b.x * rsj); zj.y = __float2bfloat16(b.y * rsj);
  *reinterpret_cast<__hip_bfloat162*>(z + (size_t)k * DDIM + t * 2) = zi;
  *reinterpret_cast<__hip_bfloat162*>(z + (size_t)(N + k) * DDIM + t * 2) = zj;
  if (t == 0) pd[k] = sij * rsi * rsj;
}

// ---------------- Kernel 2: fused sim-GEMM + exp + row-sum ----------------
// S = z z^T (bf16 MFMA, fp32 acc). Per 128x128 tile: exp(2*s), reduce over
// columns, atomicAdd into rowsum[8192]. m97 structure: BK=64, 4 waves,
// global_load_lds width 16, 2 barriers per K-step.
__global__ __launch_bounds__(256) void simloss_main(
    const __hip_bfloat16* __restrict__ z, float* __restrict__ rowsum) {
  __shared__ __hip_bfloat16 As[128 * BK];
  __shared__ __hip_bfloat16 Bs[128 * BK];
  const int tid = threadIdx.x;
  const int w = tid >> 6;
  const int l = tid & 63;
  const int row0 = blockIdx.x * 128;
  const int col0 = blockIdx.y * 128;
  const int wr = (w >> 1) * 64;  // wave row offset within tile
  const int wc = (w & 1) * 64;   // wave col offset within tile

  f32x4 acc[4][4] = {};

  const int lrow = l & 15;
  const int lko = (l >> 4) * 8;

  for (int k0 = 0; k0 < DDIM; k0 += BK) {
    // ---- stage A (rows row0..+128) and B (rows col0..+128) tiles ----
#pragma unroll
    for (int it = 0; it < 4; ++it) {
      const int m = it * 256 + tid;          // chunk id 0..1023
      const int r = m >> 3;                  // tile row 0..127
      const int c = (m & 7) << 3;            // col group (8 bf16 = 16B)
      const __hip_bfloat16* ga = z + (size_t)(row0 + r) * DDIM + (k0 + c);
      const __hip_bfloat16* gb = z + (size_t)(col0 + r) * DDIM + (k0 + c);
      const unsigned ldsoff = (unsigned)(it * 256 + w * 64) * 16;  // wave-uniform base
      __builtin_amdgcn_global_load_lds((const AS1 void*)ga,
                                       (AS3 void*)((char*)As + ldsoff), 16, 0, 0);
      __builtin_amdgcn_global_load_lds((const AS1 void*)gb,
                                       (AS3 void*)((char*)Bs + ldsoff), 16, 0, 0);
    }
    __syncthreads();
    // ---- MFMA over this K-slab ----
#pragma unroll
    for (int kk = 0; kk < BK; kk += 32) {
      bf16x8 af[4], bfv[4];
      const int lk = kk + lko;
#pragma unroll
      for (int m = 0; m < 4; ++m)
        af[m] = *reinterpret_cast<const bf16x8*>(&As[(wr + m * 16 + lrow) * BK + lk]);
#pragma unroll
      for (int n = 0; n < 4; ++n)
        bfv[n] = *reinterpret_cast<const bf16x8*>(&Bs[(wc + n * 16 + lrow) * BK + lk]);
#pragma unroll
      for (int m = 0; m < 4; ++m)
#pragma unroll
        for (int n = 0; n < 4; ++n)
          acc[m][n] = __builtin_amdgcn_mfma_f32_16x16x32_bf16(af[m], bfv[n], acc[m][n], 0, 0, 0);
    }
    __syncthreads();
  }

  // ---- epilogue: e = exp(2*s); row-reduce; atomic into rowsum ----
  // C/D layout (16x16x32): col = l&15, row = (l>>4)*4 + reg
  const float C2L2E = 2.0f * 1.44269504088896340736f;  // 2 * log2(e)
  const int lgrp = l >> 4;
  const int lcol = l & 15;
#pragma unroll
  for (int m = 0; m < 4; ++m) {
    float rs[4];
#pragma unroll
    for (int r = 0; r < 4; ++r) {
      float s = 0.0f;
#pragma unroll
      for (int n = 0; n < 4; ++n) s += exp2f(acc[m][n][r] * C2L2E);
      rs[r] = s;
    }
    // butterfly over the 16 lanes holding the 16 columns of this row set
#pragma unroll
    for (int off = 1; off < 16; off <<= 1) {
#pragma unroll
      for (int r = 0; r < 4; ++r) rs[r] += __shfl_xor(rs[r], off);
    }
    if (lcol == 0) {
      const int rowb = row0 + wr + m * 16 + lgrp * 4;
#pragma unroll
      for (int r = 0; r < 4; ++r) atomicAdd(&rowsum[rowb + r], rs[r]);
    }
  }
}

// ---------------- Kernel 3: finalize ----------------
__global__ __launch_bounds__(256) void finalize_kernel(
    const float* __restrict__ rowsum, const float* __restrict__ pd,
    float* __restrict__ out, int M, int N) {
  const int t = threadIdx.x;
  const float E2 = 7.38905609893065f;  // exp(2) — diagonal term (unit rows)
  float acc = 0.0f;
  for (int i = t; i < M; i += 256) {
    const float denom = rowsum[i] - E2;
    const int kk = (i < N) ? i : (i - N);
    acc += logf(denom) - 2.0f * pd[kk];
  }
#pragma unroll
  for (int off = 32; off; off >>= 1) acc += __shfl_down(acc, off);
  __shared__ float red[4];
  if ((t & 63) == 0) red[t >> 6] = acc;
  __syncthreads();
  if (t == 0) out[0] = (red[0] + red[1] + red[2] + red[3]) / (float)M;
}

extern "C" void kernel_launch(void* const* d_in, const int* in_sizes, int n_in,
                              void* d_out, int out_size, void* d_ws, size_t ws_size,
                              hipStream_t stream) {
  const float* ei = (const float*)d_in[0];
  const float* ej = (const float*)d_in[1];
  float* out = (float*)d_out;

  const int N = in_sizes[0] / DDIM;  // 4096
  const int M = 2 * N;               // 8192

  char* ws = (char*)d_ws;
  __hip_bfloat16* z = (__hip_bfloat16*)ws;                       // M * 512 bf16
  float* pd = (float*)(ws + (size_t)M * DDIM * 2);               // N f32
  float* rowsum = (float*)(ws + (size_t)M * DDIM * 2 + (size_t)N * 4);  // M f32

  hipMemsetAsync(rowsum, 0, (size_t)M * 4, stream);
  norm_pd_kernel<<<N, 256, 0, stream>>>(ei, ej, z, pd, N);
  dim3 grid(M / 128, M / 128);
  simloss_main<<<grid, 256, 0, stream>>>(z, rowsum);
  finalize_kernel<<<1, 256, 0, stream>>>(rowsum, pd, out, M, N);
}

// Round 2
// 116.790 us; speedup vs baseline: 1.2226x; 1.2226x over previous
//
#include <hip/hip_runtime.h>
#include <hip/hip_bf16.h>

typedef __attribute__((ext_vector_type(4))) float f32x4;
typedef __attribute__((ext_vector_type(8))) __bf16 bf16x8;

#define AS1 __attribute__((address_space(1)))
#define AS3 __attribute__((address_space(3)))

#define DDIM 512
#define BK 64

// ---------------- Kernel 1: normalize rows + positive-pair dot ----------------
__global__ __launch_bounds__(256) void norm_pd_kernel(
    const float* __restrict__ ei, const float* __restrict__ ej,
    __hip_bfloat16* __restrict__ z, float* __restrict__ pd, int N) {
  const int k = blockIdx.x;
  const int t = threadIdx.x;
  const float2 a = *reinterpret_cast<const float2*>(ei + (size_t)k * DDIM + t * 2);
  const float2 b = *reinterpret_cast<const float2*>(ej + (size_t)k * DDIM + t * 2);
  float sii = a.x * a.x + a.y * a.y;
  float sjj = b.x * b.x + b.y * b.y;
  float sij = a.x * b.x + a.y * b.y;
#pragma unroll
  for (int off = 32; off; off >>= 1) {
    sii += __shfl_down(sii, off);
    sjj += __shfl_down(sjj, off);
    sij += __shfl_down(sij, off);
  }
  __shared__ float red[3][4];
  if ((t & 63) == 0) { red[0][t >> 6] = sii; red[1][t >> 6] = sjj; red[2][t >> 6] = sij; }
  __syncthreads();
  sii = red[0][0] + red[0][1] + red[0][2] + red[0][3];
  sjj = red[1][0] + red[1][1] + red[1][2] + red[1][3];
  sij = red[2][0] + red[2][1] + red[2][2] + red[2][3];
  const float rsi = rsqrtf(sii), rsj = rsqrtf(sjj);
  __hip_bfloat162 zi, zj;
  zi.x = __float2bfloat16(a.x * rsi); zi.y = __float2bfloat16(a.y * rsi);
  zj.x = __float2bfloat16(b.x * rsj); zj.y = __float2bfloat16(b.y * rsj);
  *reinterpret_cast<__hip_bfloat162*>(z + (size_t)k * DDIM + t * 2) = zi;
  *reinterpret_cast<__hip_bfloat162*>(z + (size_t)(N + k) * DDIM + t * 2) = zj;
  if (t == 0) pd[k] = sij * rsi * rsj;
}

// ---------------- Kernel 2: fused sim-GEMM + exp + row/col-sum ----------------
// Symmetry: only tiles with bx <= by are computed. Off-diagonal tiles
// contribute row-sums (rows of the tile) AND column-sums (rows of the
// mirrored tile). Diagonal tiles contribute row-sums only (full square).
__global__ __launch_bounds__(256) void simloss_main(
    const __hip_bfloat16* __restrict__ z, float* __restrict__ rowsum) {
  const int bx = blockIdx.x;
  const int by = blockIdx.y;
  if (bx > by) return;  // lower triangle handled by symmetry

  __shared__ __hip_bfloat16 As[128 * BK];
  __shared__ __hip_bfloat16 Bs[128 * BK];
  const int tid = threadIdx.x;
  const int w = tid >> 6;
  const int l = tid & 63;
  const int row0 = bx * 128;
  const int col0 = by * 128;
  const int wr = (w >> 1) * 64;  // wave row offset within tile
  const int wc = (w & 1) * 64;   // wave col offset within tile

  f32x4 acc[4][4] = {};

  const int lrow = l & 15;
  const int lko = (l >> 4) * 8;

  for (int k0 = 0; k0 < DDIM; k0 += BK) {
#pragma unroll
    for (int it = 0; it < 4; ++it) {
      const int m = it * 256 + tid;          // chunk id 0..1023
      const int r = m >> 3;                  // tile row 0..127
      const int c = (m & 7) << 3;            // col group (8 bf16 = 16B)
      const __hip_bfloat16* ga = z + (size_t)(row0 + r) * DDIM + (k0 + c);
      const __hip_bfloat16* gb = z + (size_t)(col0 + r) * DDIM + (k0 + c);
      const unsigned ldsoff = (unsigned)(it * 256 + w * 64) * 16;  // wave-uniform base
      __builtin_amdgcn_global_load_lds((const AS1 void*)ga,
                                       (AS3 void*)((char*)As + ldsoff), 16, 0, 0);
      __builtin_amdgcn_global_load_lds((const AS1 void*)gb,
                                       (AS3 void*)((char*)Bs + ldsoff), 16, 0, 0);
    }
    __syncthreads();
#pragma unroll
    for (int kk = 0; kk < BK; kk += 32) {
      bf16x8 af[4], bfv[4];
      const int lk = kk + lko;
#pragma unroll
      for (int m = 0; m < 4; ++m)
        af[m] = *reinterpret_cast<const bf16x8*>(&As[(wr + m * 16 + lrow) * BK + lk]);
#pragma unroll
      for (int n = 0; n < 4; ++n)
        bfv[n] = *reinterpret_cast<const bf16x8*>(&Bs[(wc + n * 16 + lrow) * BK + lk]);
#pragma unroll
      for (int m = 0; m < 4; ++m)
#pragma unroll
        for (int n = 0; n < 4; ++n)
          acc[m][n] = __builtin_amdgcn_mfma_f32_16x16x32_bf16(af[m], bfv[n], acc[m][n], 0, 0, 0);
    }
    __syncthreads();
  }

  // ---- epilogue ----
  // C/D layout (16x16x32): col = l&15, row = (l>>4)*4 + reg
  const float C2L2E = 2.0f * 1.44269504088896340736f;  // 2 * log2(e)
  const int lgrp = l >> 4;
  const int lcol = l & 15;

  // exp in place
#pragma unroll
  for (int m = 0; m < 4; ++m)
#pragma unroll
    for (int n = 0; n < 4; ++n)
#pragma unroll
      for (int r = 0; r < 4; ++r)
        acc[m][n][r] = exp2f(acc[m][n][r] * C2L2E);

  // row sums: for each row (wr+m*16+lgrp*4+r), sum over the tile's 128 cols
#pragma unroll
  for (int m = 0; m < 4; ++m) {
    float rs[4];
#pragma unroll
    for (int r = 0; r < 4; ++r) {
      float s = 0.0f;
#pragma unroll
      for (int n = 0; n < 4; ++n) s += acc[m][n][r];
      rs[r] = s;
    }
#pragma unroll
    for (int off = 1; off < 16; off <<= 1) {
#pragma unroll
      for (int r = 0; r < 4; ++r) rs[r] += __shfl_xor(rs[r], off);
    }
    if (lcol == 0) {
      const int rowb = row0 + wr + m * 16 + lgrp * 4;
#pragma unroll
      for (int r = 0; r < 4; ++r) atomicAdd(&rowsum[rowb + r], rs[r]);
    }
  }

  // column sums (mirror contribution) — off-diagonal tiles only
  if (bx != by) {
#pragma unroll
    for (int n = 0; n < 4; ++n) {
      float cs = 0.0f;
#pragma unroll
      for (int m = 0; m < 4; ++m)
#pragma unroll
        for (int r = 0; r < 4; ++r) cs += acc[m][n][r];
      // combine the 4 lane-groups (rows 0..15 per group live in lanes l, l+16, l+32, l+48)
      cs += __shfl_xor(cs, 16);
      cs += __shfl_xor(cs, 32);
      if (lgrp == 0) atomicAdd(&rowsum[col0 + wc + n * 16 + lcol], cs);
    }
  }
}

// ---------------- Kernel 3: finalize ----------------
__global__ __launch_bounds__(256) void finalize_kernel(
    const float* __restrict__ rowsum, const float* __restrict__ pd,
    float* __restrict__ out, int M, int N) {
  const int t = threadIdx.x;
  const float E2 = 7.38905609893065f;  // exp(2) — diagonal term (unit rows)
  float acc = 0.0f;
  for (int i = t; i < M; i += 256) {
    const float denom = rowsum[i] - E2;
    const int kk = (i < N) ? i : (i - N);
    acc += logf(denom) - 2.0f * pd[kk];
  }
#pragma unroll
  for (int off = 32; off; off >>= 1) acc += __shfl_down(acc, off);
  __shared__ float red[4];
  if ((t & 63) == 0) red[t >> 6] = acc;
  __syncthreads();
  if (t == 0) out[0] = (red[0] + red[1] + red[2] + red[3]) / (float)M;
}

extern "C" void kernel_launch(void* const* d_in, const int* in_sizes, int n_in,
                              void* d_out, int out_size, void* d_ws, size_t ws_size,
                              hipStream_t stream) {
  const float* ei = (const float*)d_in[0];
  const float* ej = (const float*)d_in[1];
  float* out = (float*)d_out;

  const int N = in_sizes[0] / DDIM;  // 4096
  const int M = 2 * N;               // 8192

  char* ws = (char*)d_ws;
  __hip_bfloat16* z = (__hip_bfloat16*)ws;                       // M * 512 bf16
  float* pd = (float*)(ws + (size_t)M * DDIM * 2);               // N f32
  float* rowsum = (float*)(ws + (size_t)M * DDIM * 2 + (size_t)N * 4);  // M f32

  hipMemsetAsync(rowsum, 0, (size_t)M * 4, stream);
  norm_pd_kernel<<<N, 256, 0, stream>>>(ei, ej, z, pd, N);
  dim3 grid(M / 128, M / 128);
  simloss_main<<<grid, 256, 0, stream>>>(z, rowsum);
  finalize_kernel<<<1, 256, 0, stream>>>(rowsum, pd, out, M, N);
}

// Round 3
// 103.408 us; speedup vs baseline: 1.3808x; 1.1294x over previous
//
#include <hip/hip_runtime.h>
#include <hip/hip_bf16.h>

typedef __attribute__((ext_vector_type(4))) float f32x4;
typedef __attribute__((ext_vector_type(8))) __bf16 bf16x8;

#define AS1 __attribute__((address_space(1)))
#define AS3 __attribute__((address_space(3)))

#define DDIM 512
#define BK 64

// ---------------- Kernel 1: normalize rows + positive-pair dot ----------------
__global__ __launch_bounds__(256) void norm_pd_kernel(
    const float* __restrict__ ei, const float* __restrict__ ej,
    __hip_bfloat16* __restrict__ z, float* __restrict__ pd, int N) {
  const int k = blockIdx.x;
  const int t = threadIdx.x;
  const float2 a = *reinterpret_cast<const float2*>(ei + (size_t)k * DDIM + t * 2);
  const float2 b = *reinterpret_cast<const float2*>(ej + (size_t)k * DDIM + t * 2);
  float sii = a.x * a.x + a.y * a.y;
  float sjj = b.x * b.x + b.y * b.y;
  float sij = a.x * b.x + a.y * b.y;
#pragma unroll
  for (int off = 32; off; off >>= 1) {
    sii += __shfl_down(sii, off);
    sjj += __shfl_down(sjj, off);
    sij += __shfl_down(sij, off);
  }
  __shared__ float red[3][4];
  if ((t & 63) == 0) { red[0][t >> 6] = sii; red[1][t >> 6] = sjj; red[2][t >> 6] = sij; }
  __syncthreads();
  sii = red[0][0] + red[0][1] + red[0][2] + red[0][3];
  sjj = red[1][0] + red[1][1] + red[1][2] + red[1][3];
  sij = red[2][0] + red[2][1] + red[2][2] + red[2][3];
  const float rsi = rsqrtf(sii), rsj = rsqrtf(sjj);
  __hip_bfloat162 zi, zj;
  zi.x = __float2bfloat16(a.x * rsi); zi.y = __float2bfloat16(a.y * rsi);
  zj.x = __float2bfloat16(b.x * rsj); zj.y = __float2bfloat16(b.y * rsj);
  *reinterpret_cast<__hip_bfloat162*>(z + (size_t)k * DDIM + t * 2) = zi;
  *reinterpret_cast<__hip_bfloat162*>(z + (size_t)(N + k) * DDIM + t * 2) = zj;
  if (t == 0) pd[k] = sij * rsi * rsj;
}

// ---------------- Kernel 2: fused sim-GEMM + exp + row/col-sum ----------------
// Compact triangular dispatch: exactly NT*(NT+1)/2 blocks; block t decodes to
// (bx,by) with bx<=by. Off-diagonal tiles contribute row-sums AND column-sums
// (the mirrored tile's rows). Diagonal tiles contribute row-sums only.
__global__ __launch_bounds__(256) void simloss_main(
    const __hip_bfloat16* __restrict__ z, float* __restrict__ rowsum) {
  // triangular decode
  const int t0 = blockIdx.x;
  const float f = sqrtf(8.0f * (float)t0 + 1.0f);
  int by = (int)((f - 1.0f) * 0.5f);
  while ((by + 1) * (by + 2) / 2 <= t0) ++by;
  while (by * (by + 1) / 2 > t0) --by;
  const int bx = t0 - by * (by + 1) / 2;

  __shared__ __hip_bfloat16 As[128 * BK];
  __shared__ __hip_bfloat16 Bs[128 * BK];
  const int tid = threadIdx.x;
  const int w = tid >> 6;
  const int l = tid & 63;
  const int row0 = bx * 128;
  const int col0 = by * 128;
  const int wr = (w >> 1) * 64;  // wave row offset within tile
  const int wc = (w & 1) * 64;   // wave col offset within tile

  f32x4 acc[4][4] = {};

  const int lrow = l & 15;
  const int lko = (l >> 4) * 8;

  for (int k0 = 0; k0 < DDIM; k0 += BK) {
#pragma unroll
    for (int it = 0; it < 4; ++it) {
      const int m = it * 256 + tid;          // chunk id 0..1023
      const int r = m >> 3;                  // tile row 0..127
      const int c = (m & 7) << 3;            // col group (8 bf16 = 16B)
      const __hip_bfloat16* ga = z + (size_t)(row0 + r) * DDIM + (k0 + c);
      const __hip_bfloat16* gb = z + (size_t)(col0 + r) * DDIM + (k0 + c);
      const unsigned ldsoff = (unsigned)(it * 256 + w * 64) * 16;  // wave-uniform base
      __builtin_amdgcn_global_load_lds((const AS1 void*)ga,
                                       (AS3 void*)((char*)As + ldsoff), 16, 0, 0);
      __builtin_amdgcn_global_load_lds((const AS1 void*)gb,
                                       (AS3 void*)((char*)Bs + ldsoff), 16, 0, 0);
    }
    __syncthreads();
#pragma unroll
    for (int kk = 0; kk < BK; kk += 32) {
      bf16x8 af[4], bfv[4];
      const int lk = kk + lko;
#pragma unroll
      for (int m = 0; m < 4; ++m)
        af[m] = *reinterpret_cast<const bf16x8*>(&As[(wr + m * 16 + lrow) * BK + lk]);
#pragma unroll
      for (int n = 0; n < 4; ++n)
        bfv[n] = *reinterpret_cast<const bf16x8*>(&Bs[(wc + n * 16 + lrow) * BK + lk]);
#pragma unroll
      for (int m = 0; m < 4; ++m)
#pragma unroll
        for (int n = 0; n < 4; ++n)
          acc[m][n] = __builtin_amdgcn_mfma_f32_16x16x32_bf16(af[m], bfv[n], acc[m][n], 0, 0, 0);
    }
    __syncthreads();
  }

  // ---- epilogue ----
  // C/D layout (16x16x32): col = l&15, row = (l>>4)*4 + reg
  const float C2L2E = 2.0f * 1.44269504088896340736f;  // 2 * log2(e)
  const int lgrp = l >> 4;
  const int lcol = l & 15;

  // exp in place
#pragma unroll
  for (int m = 0; m < 4; ++m)
#pragma unroll
    for (int n = 0; n < 4; ++n)
#pragma unroll
      for (int r = 0; r < 4; ++r)
        acc[m][n][r] = exp2f(acc[m][n][r] * C2L2E);

  // row sums: for each row (wr+m*16+lgrp*4+r), sum over the tile's 128 cols
#pragma unroll
  for (int m = 0; m < 4; ++m) {
    float rs[4];
#pragma unroll
    for (int r = 0; r < 4; ++r) {
      float s = 0.0f;
#pragma unroll
      for (int n = 0; n < 4; ++n) s += acc[m][n][r];
      rs[r] = s;
    }
#pragma unroll
    for (int off = 1; off < 16; off <<= 1) {
#pragma unroll
      for (int r = 0; r < 4; ++r) rs[r] += __shfl_xor(rs[r], off);
    }
    if (lcol == 0) {
      const int rowb = row0 + wr + m * 16 + lgrp * 4;
#pragma unroll
      for (int r = 0; r < 4; ++r) atomicAdd(&rowsum[rowb + r], rs[r]);
    }
  }

  // column sums (mirror contribution) — off-diagonal tiles only
  if (bx != by) {
#pragma unroll
    for (int n = 0; n < 4; ++n) {
      float cs = 0.0f;
#pragma unroll
      for (int m = 0; m < 4; ++m)
#pragma unroll
        for (int r = 0; r < 4; ++r) cs += acc[m][n][r];
      // combine the 4 lane-groups (rows live in lanes l, l+16, l+32, l+48)
      cs += __shfl_xor(cs, 16);
      cs += __shfl_xor(cs, 32);
      if (lgrp == 0) atomicAdd(&rowsum[col0 + wc + n * 16 + lcol], cs);
    }
  }
}

// ---------------- Kernel 3: finalize ----------------
__global__ __launch_bounds__(256) void finalize_kernel(
    const float* __restrict__ rowsum, const float* __restrict__ pd,
    float* __restrict__ out, int M, int N) {
  const int t = threadIdx.x;
  const float E2 = 7.38905609893065f;  // exp(2) — diagonal term (unit rows)
  float acc = 0.0f;
  for (int i = t; i < M; i += 256) {
    const float denom = rowsum[i] - E2;
    const int kk = (i < N) ? i : (i - N);
    acc += logf(denom) - 2.0f * pd[kk];
  }
#pragma unroll
  for (int off = 32; off; off >>= 1) acc += __shfl_down(acc, off);
  __shared__ float red[4];
  if ((t & 63) == 0) red[t >> 6] = acc;
  __syncthreads();
  if (t == 0) out[0] = (red[0] + red[1] + red[2] + red[3]) / (float)M;
}

extern "C" void kernel_launch(void* const* d_in, const int* in_sizes, int n_in,
                              void* d_out, int out_size, void* d_ws, size_t ws_size,
                              hipStream_t stream) {
  const float* ei = (const float*)d_in[0];
  const float* ej = (const float*)d_in[1];
  float* out = (float*)d_out;

  const int N = in_sizes[0] / DDIM;  // 4096
  const int M = 2 * N;               // 8192
  const int NT = M / 128;            // 64 tiles per dim
  const int NTRI = NT * (NT + 1) / 2;  // 2080 blocks

  char* ws = (char*)d_ws;
  __hip_bfloat16* z = (__hip_bfloat16*)ws;                       // M * 512 bf16
  float* pd = (float*)(ws + (size_t)M * DDIM * 2);               // N f32
  float* rowsum = (float*)(ws + (size_t)M * DDIM * 2 + (size_t)N * 4);  // M f32

  hipMemsetAsync(rowsum, 0, (size_t)M * 4, stream);
  norm_pd_kernel<<<N, 256, 0, stream>>>(ei, ej, z, pd, N);
  simloss_main<<<NTRI, 256, 0, stream>>>(z, rowsum);
  finalize_kernel<<<1, 256, 0, stream>>>(rowsum, pd, out, M, N);
}

// Round 4
// 88.887 us; speedup vs baseline: 1.6064x; 1.1634x over previous
//
#include <hip/hip_runtime.h>
#include <hip/hip_bf16.h>

typedef __attribute__((ext_vector_type(4))) float f32x4;
typedef __attribute__((ext_vector_type(8))) __bf16 bf16x8;

#define AS1 __attribute__((address_space(1)))
#define AS3 __attribute__((address_space(3)))

#define DDIM 512
#define BK 64

// ---------------- Kernel 1: normalize rows + positive-pair dot + rowsum zero ----
__global__ __launch_bounds__(256) void norm_pd_kernel(
    const float* __restrict__ ei, const float* __restrict__ ej,
    __hip_bfloat16* __restrict__ z, float* __restrict__ pd,
    float* __restrict__ rowsum, int N) {
  const int k = blockIdx.x;
  const int t = threadIdx.x;
  const float2 a = *reinterpret_cast<const float2*>(ei + (size_t)k * DDIM + t * 2);
  const float2 b = *reinterpret_cast<const float2*>(ej + (size_t)k * DDIM + t * 2);
  float sii = a.x * a.x + a.y * a.y;
  float sjj = b.x * b.x + b.y * b.y;
  float sij = a.x * b.x + a.y * b.y;
#pragma unroll
  for (int off = 32; off; off >>= 1) {
    sii += __shfl_down(sii, off);
    sjj += __shfl_down(sjj, off);
    sij += __shfl_down(sij, off);
  }
  __shared__ float red[3][4];
  if ((t & 63) == 0) { red[0][t >> 6] = sii; red[1][t >> 6] = sjj; red[2][t >> 6] = sij; }
  __syncthreads();
  sii = red[0][0] + red[0][1] + red[0][2] + red[0][3];
  sjj = red[1][0] + red[1][1] + red[1][2] + red[1][3];
  sij = red[2][0] + red[2][1] + red[2][2] + red[2][3];
  const float rsi = rsqrtf(sii), rsj = rsqrtf(sjj);
  __hip_bfloat162 zi, zj;
  zi.x = __float2bfloat16(a.x * rsi); zi.y = __float2bfloat16(a.y * rsi);
  zj.x = __float2bfloat16(b.x * rsj); zj.y = __float2bfloat16(b.y * rsj);
  *reinterpret_cast<__hip_bfloat162*>(z + (size_t)k * DDIM + t * 2) = zi;
  *reinterpret_cast<__hip_bfloat162*>(z + (size_t)(N + k) * DDIM + t * 2) = zj;
  if (t == 0) { pd[k] = sij * rsi * rsj; rowsum[k] = 0.0f; rowsum[N + k] = 0.0f; }
}

// ---------------- Kernel 2: fused sim-GEMM + exp + row/col-sum ----------------
// Triangular dispatch with bijective XCD-chunk remap (T1). Double-buffered LDS
// with counted vmcnt (T4 "minimum 2-phase"): stage tile t+1 while computing
// tile t; s_waitcnt vmcnt(8) keeps the next tile's 8 loads in flight across
// the barrier (never drains to 0 in the main loop).
__global__ __launch_bounds__(256, 2) void simloss_main(
    const __hip_bfloat16* __restrict__ z, float* __restrict__ rowsum, int nwg) {
  // ---- XCD-chunk remap: XCD x gets a contiguous range of triangular ids ----
  const int orig = blockIdx.x;
  const int q = nwg >> 3, r = nwg & 7;
  const int xcd = orig & 7, pos = orig >> 3;
  const int t0 = (xcd < r ? xcd * (q + 1) : r * (q + 1) + (xcd - r) * q) + pos;

  // ---- triangular decode: t0 -> (bx, by), bx <= by ----
  const float f = sqrtf(8.0f * (float)t0 + 1.0f);
  int by = (int)((f - 1.0f) * 0.5f);
  while ((by + 1) * (by + 2) / 2 <= t0) ++by;
  while (by * (by + 1) / 2 > t0) --by;
  const int bx = t0 - by * (by + 1) / 2;

  __shared__ __hip_bfloat16 At[2][128 * BK];
  __shared__ __hip_bfloat16 Bt[2][128 * BK];
  const int tid = threadIdx.x;
  const int w = tid >> 6;
  const int l = tid & 63;
  const int row0 = bx * 128;
  const int col0 = by * 128;
  const int wr = (w >> 1) * 64;  // wave row offset within tile
  const int wc = (w & 1) * 64;   // wave col offset within tile

  f32x4 acc[4][4] = {};

  const int lrow = l & 15;
  const int lko = (l >> 4) * 8;

  // stage one K-tile (A rows row0.., B rows col0..) into buffer nb
  auto stage = [&](int nb, int k0) {
#pragma unroll
    for (int it = 0; it < 4; ++it) {
      const int m = it * 256 + tid;          // chunk id 0..1023
      const int rr = m >> 3;                 // tile row 0..127
      const int c = (m & 7) << 3;            // col group (8 bf16 = 16B)
      const __hip_bfloat16* ga = z + (size_t)(row0 + rr) * DDIM + (k0 + c);
      const __hip_bfloat16* gb = z + (size_t)(col0 + rr) * DDIM + (k0 + c);
      const unsigned ldsoff = (unsigned)(it * 256 + w * 64) * 16;  // wave-uniform base
      __builtin_amdgcn_global_load_lds((const AS1 void*)ga,
                                       (AS3 void*)((char*)&At[nb][0] + ldsoff), 16, 0, 0);
      __builtin_amdgcn_global_load_lds((const AS1 void*)gb,
                                       (AS3 void*)((char*)&Bt[nb][0] + ldsoff), 16, 0, 0);
    }
  };

  auto compute = [&](int nb) {
#pragma unroll
    for (int kk = 0; kk < BK; kk += 32) {
      bf16x8 af[4], bfv[4];
      const int lk = kk + lko;
#pragma unroll
      for (int m = 0; m < 4; ++m)
        af[m] = *reinterpret_cast<const bf16x8*>(&At[nb][(wr + m * 16 + lrow) * BK + lk]);
#pragma unroll
      for (int n = 0; n < 4; ++n)
        bfv[n] = *reinterpret_cast<const bf16x8*>(&Bt[nb][(wc + n * 16 + lrow) * BK + lk]);
      __builtin_amdgcn_s_setprio(1);
#pragma unroll
      for (int m = 0; m < 4; ++m)
#pragma unroll
        for (int n = 0; n < 4; ++n)
          acc[m][n] = __builtin_amdgcn_mfma_f32_16x16x32_bf16(af[m], bfv[n], acc[m][n], 0, 0, 0);
      __builtin_amdgcn_s_setprio(0);
    }
  };

  // ---- pipelined K-loop: 8 tiles of BK=64 ----
  stage(0, 0);
  int nb = 0;
  for (int t = 0; t < (DDIM / BK) - 1; ++t) {
    stage(nb ^ 1, (t + 1) * BK);                       // prefetch next tile
    asm volatile("s_waitcnt vmcnt(8)" ::: "memory");   // tile t's loads landed
    __builtin_amdgcn_s_barrier();
    __builtin_amdgcn_sched_barrier(0);
    compute(nb);
    __builtin_amdgcn_sched_barrier(0);
    __builtin_amdgcn_s_barrier();                      // buf nb free for overwrite
    nb ^= 1;
  }
  asm volatile("s_waitcnt vmcnt(0)" ::: "memory");
  __builtin_amdgcn_s_barrier();
  compute(nb);

  // ---- epilogue ----
  // C/D layout (16x16x32): col = l&15, row = (l>>4)*4 + reg
  const float C2L2E = 2.0f * 1.44269504088896340736f;  // 2 * log2(e)
  const int lgrp = l >> 4;
  const int lcol = l & 15;

#pragma unroll
  for (int m = 0; m < 4; ++m)
#pragma unroll
    for (int n = 0; n < 4; ++n)
#pragma unroll
      for (int rg = 0; rg < 4; ++rg)
        acc[m][n][rg] = exp2f(acc[m][n][rg] * C2L2E);

  // row sums: row (row0 + wr + m*16 + lgrp*4 + rg), summed over tile's 128 cols
#pragma unroll
  for (int m = 0; m < 4; ++m) {
    float rs[4];
#pragma unroll
    for (int rg = 0; rg < 4; ++rg) {
      float s = 0.0f;
#pragma unroll
      for (int n = 0; n < 4; ++n) s += acc[m][n][rg];
      rs[rg] = s;
    }
#pragma unroll
    for (int off = 1; off < 16; off <<= 1) {
#pragma unroll
      for (int rg = 0; rg < 4; ++rg) rs[rg] += __shfl_xor(rs[rg], off);
    }
    if (lcol == 0) {
      const int rowb = row0 + wr + m * 16 + lgrp * 4;
#pragma unroll
      for (int rg = 0; rg < 4; ++rg) atomicAdd(&rowsum[rowb + rg], rs[rg]);
    }
  }

  // column sums (mirror contribution) — off-diagonal tiles only
  if (bx != by) {
#pragma unroll
    for (int n = 0; n < 4; ++n) {
      float cs = 0.0f;
#pragma unroll
      for (int m = 0; m < 4; ++m)
#pragma unroll
        for (int rg = 0; rg < 4; ++rg) cs += acc[m][n][rg];
      cs += __shfl_xor(cs, 16);
      cs += __shfl_xor(cs, 32);
      if (lgrp == 0) atomicAdd(&rowsum[col0 + wc + n * 16 + lcol], cs);
    }
  }
}

// ---------------- Kernel 3: finalize ----------------
__global__ __launch_bounds__(256) void finalize_kernel(
    const float* __restrict__ rowsum, const float* __restrict__ pd,
    float* __restrict__ out, int M, int N) {
  const int t = threadIdx.x;
  const float E2 = 7.38905609893065f;  // exp(2) — diagonal term (unit rows)
  float acc = 0.0f;
  for (int i = t; i < M; i += 256) {
    const float denom = rowsum[i] - E2;
    const int kk = (i < N) ? i : (i - N);
    acc += logf(denom) - 2.0f * pd[kk];
  }
#pragma unroll
  for (int off = 32; off; off >>= 1) acc += __shfl_down(acc, off);
  __shared__ float red[4];
  if ((t & 63) == 0) red[t >> 6] = acc;
  __syncthreads();
  if (t == 0) out[0] = (red[0] + red[1] + red[2] + red[3]) / (float)M;
}

extern "C" void kernel_launch(void* const* d_in, const int* in_sizes, int n_in,
                              void* d_out, int out_size, void* d_ws, size_t ws_size,
                              hipStream_t stream) {
  const float* ei = (const float*)d_in[0];
  const float* ej = (const float*)d_in[1];
  float* out = (float*)d_out;

  const int N = in_sizes[0] / DDIM;  // 4096
  const int M = 2 * N;               // 8192
  const int NT = M / 128;            // 64 tiles per dim
  const int NTRI = NT * (NT + 1) / 2;  // 2080 blocks

  char* ws = (char*)d_ws;
  __hip_bfloat16* z = (__hip_bfloat16*)ws;                       // M * 512 bf16
  float* pd = (float*)(ws + (size_t)M * DDIM * 2);               // N f32
  float* rowsum = (float*)(ws + (size_t)M * DDIM * 2 + (size_t)N * 4);  // M f32

  norm_pd_kernel<<<N, 256, 0, stream>>>(ei, ej, z, pd, rowsum, N);
  simloss_main<<<NTRI, 256, 0, stream>>>(z, rowsum, NTRI);
  finalize_kernel<<<1, 256, 0, stream>>>(rowsum, pd, out, M, N);
}

// Round 5
// 84.691 us; speedup vs baseline: 1.6859x; 1.0495x over previous
//
#include <hip/hip_runtime.h>
#include <hip/hip_bf16.h>

typedef __attribute__((ext_vector_type(4))) float f32x4;
typedef __attribute__((ext_vector_type(8))) __bf16 bf16x8;

#define AS1 __attribute__((address_space(1)))
#define AS3 __attribute__((address_space(3)))

#define DDIM 512
#define BK 64

// ---------------- Kernel 1: normalize rows + positive-pair dot + rowsum zero ----
__global__ __launch_bounds__(256) void norm_pd_kernel(
    const float* __restrict__ ei, const float* __restrict__ ej,
    __hip_bfloat16* __restrict__ z, float* __restrict__ pd,
    float* __restrict__ rowsum, int N) {
  const int k = blockIdx.x;
  const int t = threadIdx.x;
  const float2 a = *reinterpret_cast<const float2*>(ei + (size_t)k * DDIM + t * 2);
  const float2 b = *reinterpret_cast<const float2*>(ej + (size_t)k * DDIM + t * 2);
  float sii = a.x * a.x + a.y * a.y;
  float sjj = b.x * b.x + b.y * b.y;
  float sij = a.x * b.x + a.y * b.y;
#pragma unroll
  for (int off = 32; off; off >>= 1) {
    sii += __shfl_down(sii, off);
    sjj += __shfl_down(sjj, off);
    sij += __shfl_down(sij, off);
  }
  __shared__ float red[3][4];
  if ((t & 63) == 0) { red[0][t >> 6] = sii; red[1][t >> 6] = sjj; red[2][t >> 6] = sij; }
  __syncthreads();
  sii = red[0][0] + red[0][1] + red[0][2] + red[0][3];
  sjj = red[1][0] + red[1][1] + red[1][2] + red[1][3];
  sij = red[2][0] + red[2][1] + red[2][2] + red[2][3];
  const float rsi = rsqrtf(sii), rsj = rsqrtf(sjj);
  __hip_bfloat162 zi, zj;
  zi.x = __float2bfloat16(a.x * rsi); zi.y = __float2bfloat16(a.y * rsi);
  zj.x = __float2bfloat16(b.x * rsj); zj.y = __float2bfloat16(b.y * rsj);
  *reinterpret_cast<__hip_bfloat162*>(z + (size_t)k * DDIM + t * 2) = zi;
  *reinterpret_cast<__hip_bfloat162*>(z + (size_t)(N + k) * DDIM + t * 2) = zj;
  if (t == 0) { pd[k] = sij * rsi * rsj; rowsum[k] = 0.0f; rowsum[N + k] = 0.0f; }
}

// ---------------- Kernel 2: 256x256-tile 8-wave 4-phase fused sim-GEMM ----------
// Per-wave output 128x64 (8x4 frags). LDS: 2 buf x 4 half-tiles (A_lo,A_hi,
// B_lo,B_hi) x 16KB = 128 KiB. Stage for tile t+2 issued in the phase after
// the last read of the slot it overwrites. Counted vmcnt(8) at K-tile
// boundaries only. Bank-conflict-free frag reads via XOR-swizzled layout
// applied on the (per-lane) GLOBAL source of global_load_lds; LDS dest linear.
//
// Swizzle: half-tile = 128 rows x 64 cols bf16, 16B chunks c=0..7 per row;
// stored chunk index = r*8 + (c ^ (r&7)).

#define BAR() do { __builtin_amdgcn_sched_barrier(0); __builtin_amdgcn_s_barrier(); \
                   __builtin_amdgcn_sched_barrier(0); } while (0)
#define VM_WAIT8() asm volatile("s_waitcnt vmcnt(8)" ::: "memory")
#define VM_WAIT0() asm volatile("s_waitcnt vmcnt(0)" ::: "memory")

#define READ_A(MH)                                                            \
  do {                                                                        \
    _Pragma("unroll") for (int mf = 0; mf < 4; ++mf)                          \
    _Pragma("unroll") for (int kk = 0; kk < 2; ++kk) {                        \
      const int rl = (MH) * 64 + mf * 16 + (l & 15);                          \
      Af[mf][kk] = *reinterpret_cast<const bf16x8*>(                          \
          abase + rl * 128 + ((((kk * 4) + (l >> 4)) ^ (l & 7)) << 4));       \
    }                                                                         \
  } while (0)

#define READ_B(DST, NH)                                                       \
  do {                                                                        \
    _Pragma("unroll") for (int nf = 0; nf < 2; ++nf)                          \
    _Pragma("unroll") for (int kk = 0; kk < 2; ++kk) {                        \
      const int crl = (wn & 1) * 64 + (NH) * 32 + nf * 16 + (l & 15);         \
      DST[nf][kk] = *reinterpret_cast<const bf16x8*>(                         \
          bbase + crl * 128 + ((((kk * 4) + (l >> 4)) ^ (l & 7)) << 4));      \
    }                                                                         \
  } while (0)

#define MMA(BREG, MH, NH)                                                     \
  do {                                                                        \
    __builtin_amdgcn_s_setprio(1);                                            \
    _Pragma("unroll") for (int mf = 0; mf < 4; ++mf)                          \
    _Pragma("unroll") for (int nf = 0; nf < 2; ++nf)                          \
    _Pragma("unroll") for (int kk = 0; kk < 2; ++kk)                          \
      acc[(MH) * 4 + mf][(NH) * 2 + nf] =                                     \
          __builtin_amdgcn_mfma_f32_16x16x32_bf16(                            \
              Af[mf][kk], BREG[nf][kk], acc[(MH) * 4 + mf][(NH) * 2 + nf],    \
              0, 0, 0);                                                       \
    __builtin_amdgcn_s_setprio(0);                                            \
  } while (0)

__global__ __launch_bounds__(512, 2) void simloss_main(
    const __hip_bfloat16* __restrict__ z, float* __restrict__ rowsum, int nwg) {
  // ---- bijective XCD-chunk remap (nwg = 528 = 8*66) ----
  const int orig = blockIdx.x;
  const int q = nwg >> 3, r8 = nwg & 7;
  const int xcd = orig & 7, pos = orig >> 3;
  const int t0 = (xcd < r8 ? xcd * (q + 1) : r8 * (q + 1) + (xcd - r8) * q) + pos;

  // ---- triangular decode: t0 -> (bx, by), bx <= by ----
  const float ff = sqrtf(8.0f * (float)t0 + 1.0f);
  int by = (int)((ff - 1.0f) * 0.5f);
  while ((by + 1) * (by + 2) / 2 <= t0) ++by;
  while (by * (by + 1) / 2 > t0) --by;
  const int bx = t0 - by * (by + 1) / 2;

  const int row0 = bx * 256;
  const int col0 = by * 256;

  __shared__ __hip_bfloat16 lds[2][4][128 * 64];  // [buf][Alo,Ahi,Blo,Bhi][16KB]

  const int tid = threadIdx.x;
  const int w = tid >> 6;    // wave 0..7
  const int l = tid & 63;
  const int wm = w >> 2;     // 0..1  (row half of tile)
  const int wn = w & 3;      // 0..3  (64-col strip)

  f32x4 acc[8][4] = {};

  // stage one 128x64 half-tile into lds[p][half]; global source pre-swizzled
  auto stage_half = [&](int p, int half, int baserow, int k0) {
#pragma unroll
    for (int qq = 0; qq < 2; ++qq) {
      const int rr = w * 16 + qq * 8 + (l >> 3);
      const int cc = (l & 7) ^ ((l >> 3) & 7);
      const __hip_bfloat16* g = z + (size_t)(baserow + rr) * DDIM + k0 + cc * 8;
      char* dst = (char*)&lds[p][half][0] + (unsigned)(w * 2 + qq) * 1024;  // wave-uniform
      __builtin_amdgcn_global_load_lds((const AS1 void*)g, (AS3 void*)dst, 16, 0, 0);
    }
  };

  // ---- prologue: tile0 -> buf0, tile1 -> buf1 ----
  stage_half(0, 0, row0, 0);        stage_half(0, 1, row0 + 128, 0);
  stage_half(0, 2, col0, 0);        stage_half(0, 3, col0 + 128, 0);
  stage_half(1, 0, row0, BK);       stage_half(1, 1, row0 + 128, BK);
  stage_half(1, 2, col0, BK);       stage_half(1, 3, col0 + 128, BK);
  VM_WAIT8();   // tile0's 8 loads landed
  BAR();

  bf16x8 Af[4][2], B0r[2][2], B1r[2][2];

  // ---- K-loop: 8 tiles of BK=64, 4 phases each ----
  for (int t = 0; t < 8; ++t) {
    const int p = t & 1;
    const int k2 = (t + 2) * BK;
    const char* abase = (const char*)&lds[p][wm][0];
    const char* bbase = (const char*)&lds[p][2 + (wn >> 1)][0];

    // ph0: (mh0, nh0)
    READ_A(0);
    READ_B(B0r, 0);
    MMA(B0r, 0, 0);
    BAR();
    // ph1: (mh0, nh1)
    READ_B(B1r, 1);
    MMA(B1r, 0, 1);
    BAR();
    // ph2: (mh1, nh1) — B slots fully read (ph1-end barrier) -> stage B(t+2)
    if (t < 6) { stage_half(p, 2, col0, k2); stage_half(p, 3, col0 + 128, k2); }
    READ_A(1);
    MMA(B1r, 1, 1);
    BAR();
    // ph3: (mh1, nh0) — A slots fully read (ph2-end barrier) -> stage A(t+2)
    if (t < 6) { stage_half(p, 0, row0, k2); stage_half(p, 1, row0 + 128, k2); }
    MMA(B0r, 1, 0);
    if (t < 6) { VM_WAIT8(); }        // all of tile t+1's loads landed
    else if (t == 6) { VM_WAIT0(); }  // drain tile 7's loads
    BAR();
  }

  // ---- epilogue ----
  // frag (fi, cj): rows row0 + wm*128 + fi*16 + lgrp*4 + rg, col col0 + wn*64 + cj*16 + lcol
  const float C2L2E = 2.0f * 1.44269504088896340736f;  // 2 * log2(e)
  const int lgrp = l >> 4;
  const int lcol = l & 15;

#pragma unroll
  for (int fi = 0; fi < 8; ++fi)
#pragma unroll
    for (int cj = 0; cj < 4; ++cj)
#pragma unroll
      for (int rg = 0; rg < 4; ++rg)
        acc[fi][cj][rg] = exp2f(acc[fi][cj][rg] * C2L2E);

  // row sums over the wave's 64 cols
#pragma unroll
  for (int fi = 0; fi < 8; ++fi) {
    float rs[4];
#pragma unroll
    for (int rg = 0; rg < 4; ++rg) {
      float s = 0.0f;
#pragma unroll
      for (int cj = 0; cj < 4; ++cj) s += acc[fi][cj][rg];
      rs[rg] = s;
    }
#pragma unroll
    for (int off = 1; off < 16; off <<= 1) {
#pragma unroll
      for (int rg = 0; rg < 4; ++rg) rs[rg] += __shfl_xor(rs[rg], off);
    }
    if (lcol == 0) {
      const int rowb = row0 + wm * 128 + fi * 16 + lgrp * 4;
#pragma unroll
      for (int rg = 0; rg < 4; ++rg) atomicAdd(&rowsum[rowb + rg], rs[rg]);
    }
  }

  // column sums (mirror) — off-diagonal tiles only
  if (bx != by) {
#pragma unroll
    for (int cj = 0; cj < 4; ++cj) {
      float cs = 0.0f;
#pragma unroll
      for (int fi = 0; fi < 8; ++fi)
#pragma unroll
        for (int rg = 0; rg < 4; ++rg) cs += acc[fi][cj][rg];
      cs += __shfl_xor(cs, 16);
      cs += __shfl_xor(cs, 32);
      if (lgrp == 0) atomicAdd(&rowsum[col0 + wn * 64 + cj * 16 + lcol], cs);
    }
  }
}

// ---------------- Kernel 3: finalize ----------------
__global__ __launch_bounds__(256) void finalize_kernel(
    const float* __restrict__ rowsum, const float* __restrict__ pd,
    float* __restrict__ out, int M, int N) {
  const int t = threadIdx.x;
  const float E2 = 7.38905609893065f;  // exp(2) — diagonal term (unit rows)
  float acc = 0.0f;
  for (int i = t; i < M; i += 256) {
    const float denom = rowsum[i] - E2;
    const int kk = (i < N) ? i : (i - N);
    acc += logf(denom) - 2.0f * pd[kk];
  }
#pragma unroll
  for (int off = 32; off; off >>= 1) acc += __shfl_down(acc, off);
  __shared__ float red[4];
  if ((t & 63) == 0) red[t >> 6] = acc;
  __syncthreads();
  if (t == 0) out[0] = (red[0] + red[1] + red[2] + red[3]) / (float)M;
}

extern "C" void kernel_launch(void* const* d_in, const int* in_sizes, int n_in,
                              void* d_out, int out_size, void* d_ws, size_t ws_size,
                              hipStream_t stream) {
  const float* ei = (const float*)d_in[0];
  const float* ej = (const float*)d_in[1];
  float* out = (float*)d_out;

  const int N = in_sizes[0] / DDIM;  // 4096
  const int M = 2 * N;               // 8192
  const int NT = M / 256;            // 32 tiles per dim
  const int NTRI = NT * (NT + 1) / 2;  // 528 blocks

  char* ws = (char*)d_ws;
  __hip_bfloat16* z = (__hip_bfloat16*)ws;                       // M * 512 bf16
  float* pd = (float*)(ws + (size_t)M * DDIM * 2);               // N f32
  float* rowsum = (float*)(ws + (size_t)M * DDIM * 2 + (size_t)N * 4);  // M f32

  norm_pd_kernel<<<N, 256, 0, stream>>>(ei, ej, z, pd, rowsum, N);
  simloss_main<<<NTRI, 512, 0, stream>>>(z, rowsum, NTRI);
  finalize_kernel<<<1, 256, 0, stream>>>(rowsum, pd, out, M, N);
}